// Round 9
// baseline (54.243 us; speedup 1.0000x reference)
//
#include <hip/hip_runtime.h>
#include <hip/hip_bf16.h>
#include <math.h>

// X: [32,3,256,256]; 8192 independent 16x16 patches (conv pad=1 zero-pads per
// patch). One wave = one patch. TWO kernels total (prep eliminated).
//
// v10 = v6/v8 + in-block B build + store-based output (no global atomics).
//  - B matrix (72x32 bf16) + bias vectors built PER BLOCK in LDS by threads
//    <72 / 128..207, one __syncthreads: deletes the serial prep launch.
//  - each patch stores {tTA,tTB,tBA,tBB} per channel to Sout[patch][8][4]
//    (plain dwordx4, no zero-init needed, no RMW tail). head phase A reduces
//    Sout into syl[128] via LDS atomics with a (c-lane x patch-group)
//    assignment (coalesced loads, ~4-way bank conflicts only).
// v8 carried: minimal halo zero. v6 carried: packed-f32 relu/accumulate,
// XCD swizzle. v2 carried: pre-packed bf16 PAIR slabs (p2 = pack(v,v+1),
// px18 = pack(v,v+18)); B k''-slot order matches; hot loop = 4 aligned
// ds_read_b32 -> 5 MFMAs; bias in MFMA C operands; router acc chained via C.

typedef short bf16x8 __attribute__((ext_vector_type(8)));
typedef float f32x4 __attribute__((ext_vector_type(4)));
typedef float pf2 __attribute__((ext_vector_type(2)));

__device__ __forceinline__ int cellOf(int r) {
    int rr = r + 4;   // padded coordinate; cells of 66 in [0,264)
    return (rr >= 66) + (rr >= 132) + (rr >= 198);
}

__device__ __forceinline__ unsigned int packbf2(float lo, float hi) {
    __hip_bfloat162 h = __float22bfloat162_rn(make_float2(lo, hi));
    unsigned int u;
    __builtin_memcpy(&u, &h, 4);
    return u;
}

// MFMA core shared by both step flavors: PKV = uint4 of A-fragment dwords.
#define MFMA_CORE(PKV, ACCJ) do {                                           \
    const bf16x8 afr = __builtin_bit_cast(bf16x8, (PKV));                   \
    const f32x4 a0 = __builtin_amdgcn_mfma_f32_16x16x32_bf16(afr, bfr0, cbv0, 0, 0, 0); \
    const f32x4 a1 = __builtin_amdgcn_mfma_f32_16x16x32_bf16(afr, bfr1, cbv1, 0, 0, 0); \
    const f32x4 a2 = __builtin_amdgcn_mfma_f32_16x16x32_bf16(afr, bfr2, cbv2, 0, 0, 0); \
    const f32x4 a3 = __builtin_amdgcn_mfma_f32_16x16x32_bf16(afr, bfr3, cbv3, 0, 0, 0); \
    a4acc = __builtin_amdgcn_mfma_f32_16x16x32_bf16(afr, bfr4, a4acc, 0, 0, 0); \
    const pf2 z2_ = {0.f, 0.f};                                             \
    {                                                                       \
        const pf2 l_ = __builtin_elementwise_max((pf2)__builtin_shufflevector(a0, a0, 0, 1), z2_); \
        const pf2 h_ = __builtin_elementwise_max((pf2)__builtin_shufflevector(a0, a0, 2, 3), z2_); \
        pall2[0] += l_ + h_;                                                \
        if (ACCJ) psb2[0] += l_ * jm2lo + h_ * jm2hi;                       \
    }                                                                       \
    {                                                                       \
        const pf2 l_ = __builtin_elementwise_max((pf2)__builtin_shufflevector(a1, a1, 0, 1), z2_); \
        const pf2 h_ = __builtin_elementwise_max((pf2)__builtin_shufflevector(a1, a1, 2, 3), z2_); \
        pall2[1] += l_ + h_;                                                \
        if (ACCJ) psb2[1] += l_ * jm2lo + h_ * jm2hi;                       \
    }                                                                       \
    {                                                                       \
        const pf2 l_ = __builtin_elementwise_max((pf2)__builtin_shufflevector(a2, a2, 0, 1), z2_); \
        const pf2 h_ = __builtin_elementwise_max((pf2)__builtin_shufflevector(a2, a2, 2, 3), z2_); \
        pall2[2] += l_ + h_;                                                \
        if (ACCJ) psb2[2] += l_ * jm2lo + h_ * jm2hi;                       \
    }                                                                       \
    {                                                                       \
        const pf2 l_ = __builtin_elementwise_max((pf2)__builtin_shufflevector(a3, a3, 0, 1), z2_); \
        const pf2 h_ = __builtin_elementwise_max((pf2)__builtin_shufflevector(a3, a3, 2, 3), z2_); \
        pall2[3] += l_ + h_;                                                \
        if (ACCJ) psb2[3] += l_ * jm2lo + h_ * jm2hi;                       \
    }                                                                       \
} while (0)

#define CONV_STEP(SB, ACCJ) do {                                            \
    uint4 pkv;                                                              \
    pkv.x = pkw[offp0 + (SB)];                                              \
    pkv.y = pkw[offp1 + (SB)];                                              \
    pkv.z = pkw[offp2 + (SB)];                                              \
    pkv.w = pkw[offp3 + (SB)];                                              \
    MFMA_CORE(pkv, ACCJ);                                                   \
} while (0)

// softmax + gate (all 64 lanes; lane's expert e = lid&7)
#define GATES_FROM_RSUM()                                                   \
    rsum += __shfl_xor(rsum, 16);                                           \
    rsum += __shfl_xor(rsum, 32);                                           \
    float gv[4];                                                            \
    {                                                                       \
        float lg = rsum * (1.f / 256.f);                                    \
        float mx = fmaxf(lg, __shfl_xor(lg, 1));                            \
        mx = fmaxf(mx, __shfl_xor(mx, 2));                                  \
        mx = fmaxf(mx, __shfl_xor(mx, 4));                                  \
        float ex = __expf(lg - mx);                                         \
        float s = ex;                                                       \
        s += __shfl_xor(s, 1); s += __shfl_xor(s, 2); s += __shfl_xor(s, 4);\
        float sc = ex / s;                                                  \
        float g = sc / (1.f + __expf(-(sc - thr) * 10.f));                  \
        float gs = g;                                                       \
        gs += __shfl_xor(gs, 1); gs += __shfl_xor(gs, 2); gs += __shfl_xor(gs, 4); \
        float gn = g / (gs + 1e-9f);                                        \
        const int gb = (lid & 56);                                          \
        const int hb = (lid >> 3) & 1;                                      \
        gv[0] = __shfl(gn, gb | (0 + hb));                                  \
        gv[1] = __shfl(gn, gb | (2 + hb));                                  \
        gv[2] = __shfl(gn, gb | (4 + hb));                                  \
        gv[3] = __shfl(gn, gb | (6 + hb));                                  \
    }

// ---------------- fused expert+router conv, store-based output ----------------
__global__ __launch_bounds__(256, 4) void fused_kernel(
    const float* __restrict__ X, const float* __restrict__ ew,
    const float* __restrict__ ebg, const float* __restrict__ pw,
    const float* __restrict__ pb, const float* __restrict__ keys,
    const float* __restrict__ thr_p, float* __restrict__ Sout)
{
    // per-wave packed pair slabs: p2 at [0..976), px18 stored at 976+i
    __shared__ __align__(16) unsigned int pk[4][1952];
    __shared__ __align__(16) unsigned short Bgs[2304];   // 72 x 32 bf16
    __shared__ float cbfs[80];

    const int t = threadIdx.x;
    const int wid = t >> 6, lid = t & 63;
    const int r16 = lid & 15, kb = lid >> 4;

    // ---- in-block B + bias build (replaces prep_kernel) ----
    if (t < 72) {
        float sv[32];
        #pragma unroll
        for (int s = 0; s < 32; ++s) {
            int q, kx; bool zz = false;
            if (s < 16)       { q = s >> 1;  kx = s & 1; }
            else if (s < 18)  { q = 8;       kx = s - 16; }
            else if (s < 26)  { q = s - 18;  kx = 2; }
            else if (s == 26) { q = 8;       kx = 2; }
            else              { q = 0; kx = 0; zz = true; }
            const int ky = q / 3, c = q - ky * 3;
            const int widx = c * 9 + ky * 3 + kx;
            float a;
            if (t < 64) {
                a = ew[t * 27 + widx];
            } else {
                const int e = t - 64;
                a = 0.f;
                #pragma unroll
                for (int o = 0; o < 16; ++o)
                    a += keys[e * 16 + o] * pw[o * 27 + widx];
            }
            sv[s] = zz ? 0.f : a;
        }
        uint4 q0, q1, q2v, q3v;
        q0.x  = packbf2(sv[0],  sv[1]);  q0.y  = packbf2(sv[2],  sv[3]);
        q0.z  = packbf2(sv[4],  sv[5]);  q0.w  = packbf2(sv[6],  sv[7]);
        q1.x  = packbf2(sv[8],  sv[9]);  q1.y  = packbf2(sv[10], sv[11]);
        q1.z  = packbf2(sv[12], sv[13]); q1.w  = packbf2(sv[14], sv[15]);
        q2v.x = packbf2(sv[16], sv[17]); q2v.y = packbf2(sv[18], sv[19]);
        q2v.z = packbf2(sv[20], sv[21]); q2v.w = packbf2(sv[22], sv[23]);
        q3v.x = packbf2(sv[24], sv[25]); q3v.y = packbf2(sv[26], sv[27]);
        q3v.z = packbf2(sv[28], sv[29]); q3v.w = packbf2(sv[30], sv[31]);
        uint4* dst = reinterpret_cast<uint4*>(&Bgs[t * 32]);
        dst[0] = q0; dst[1] = q1; dst[2] = q2v; dst[3] = q3v;
    } else if (t >= 128 && t < 208) {
        const int i = t - 128;
        float c;
        if (i < 64) {
            c = ebg[i];
        } else {
            const int e = (i - 64) & 7;
            c = 0.f;
            #pragma unroll
            for (int o = 0; o < 16; ++o) c += keys[e * 16 + o] * pb[o];
        }
        cbfs[i] = c;
    }

    // XCD swizzle: all 64 blocks of one image land on one XCD (2048%8==0)
    const int wgid = blockIdx.x;
    const int virt = (wgid & 7) * 256 + (wgid >> 3);

    const int gp = (virt << 2) + wid;             // patch id 0..8191
    const int b = gp >> 8;
    const int pi = (gp >> 4) & 15, pj = gp & 15;
    const int rbase = pi << 4, cbase = pj << 4;

    unsigned int* pkw = pk[wid];
    const float thr = thr_p[0];

    // ---- issue all global loads up front (in flight together) ----
    const int lr = lid >> 2, lq = lid & 3;
    const float* xb = X + ((b * 3) << 16) + ((rbase + lr) << 8) + cbase + (lq << 2);
    const float4 xv0 = *reinterpret_cast<const float4*>(xb);
    const float4 xv1 = *reinterpret_cast<const float4*>(xb + 65536);
    const float4 xv2 = *reinterpret_cast<const float4*>(xb + 131072);

    // ---- minimal halo zero (only dwords the loop can read as halo) ----
    if (lid < 54) {
        pkw[lid] = 0u;             // p2 row 0
        pkw[918 + lid] = 0u;       // p2 row 17
        pkw[976 + lid] = 0u;       // px row 0
        pkw[1894 + lid] = 0u;      // px row 17
    }
    if (lid < 48) {
        const int y3 = lid / 3;
        const int cp = lid - y3 * 3;
        pkw[976 + (y3 + 1) * 54 + cp * 18 + 16] = 0u;   // px idx16 (halo col 17)
    }

    __syncthreads();   // B/cbf built + halo zeroed

    const bf16x8 bfr0 = *reinterpret_cast<const bf16x8*>(&Bgs[(r16) * 32 + (kb << 3)]);
    const bf16x8 bfr1 = *reinterpret_cast<const bf16x8*>(&Bgs[(16 + r16) * 32 + (kb << 3)]);
    const bf16x8 bfr2 = *reinterpret_cast<const bf16x8*>(&Bgs[(32 + r16) * 32 + (kb << 3)]);
    const bf16x8 bfr3 = *reinterpret_cast<const bf16x8*>(&Bgs[(48 + r16) * 32 + (kb << 3)]);
    const bf16x8 bfr4 = *reinterpret_cast<const bf16x8*>(&Bgs[(64 + (r16 & 7)) * 32 + (kb << 3)]);

    const float cbs0 = cbfs[r16];
    const float cbs1 = cbfs[16 + r16];
    const float cbs2 = cbfs[32 + r16];
    const float cbs3 = cbfs[48 + r16];
    const float cbs4 = cbfs[64 + r16];

    // ---- build packed pair slabs straight from registers ----
    float s0 = __shfl_up(xv0.w, 1);
    float s1 = __shfl_up(xv1.w, 1);
    float s2 = __shfl_up(xv2.w, 1);
    const float c0p = (lq == 0) ? 0.f : s0;   // col 4lq (left neighbor / halo)
    const float c1p = (lq == 0) ? 0.f : s1;
    const float c2p = (lq == 0) ? 0.f : s2;
    float nxx = __shfl_down(xv0.x, 4);        // next row, channel 0 (for px c2)
    float nxy = __shfl_down(xv0.y, 4);
    float nxz = __shfl_down(xv0.z, 4);
    float nxw = __shfl_down(xv0.w, 4);
    if (lr == 15) { nxx = 0.f; nxy = 0.f; nxz = 0.f; nxw = 0.f; }

    {
        const int y = lr + 1;
        const int b2 = y * 54 + (lq << 2);            // p2: pairs (col p, col p+1)
        unsigned int u0, u1, u2, u3;
        u0 = packbf2(c0p,   xv0.x); u1 = packbf2(xv0.x, xv0.y);
        u2 = packbf2(xv0.y, xv0.z); u3 = packbf2(xv0.z, xv0.w);
        *reinterpret_cast<uint2*>(&pkw[b2])      = make_uint2(u0, u1);
        *reinterpret_cast<uint2*>(&pkw[b2 + 2])  = make_uint2(u2, u3);
        u0 = packbf2(c1p,   xv1.x); u1 = packbf2(xv1.x, xv1.y);
        u2 = packbf2(xv1.y, xv1.z); u3 = packbf2(xv1.z, xv1.w);
        *reinterpret_cast<uint2*>(&pkw[b2 + 18]) = make_uint2(u0, u1);
        *reinterpret_cast<uint2*>(&pkw[b2 + 20]) = make_uint2(u2, u3);
        u0 = packbf2(c2p,   xv2.x); u1 = packbf2(xv2.x, xv2.y);
        u2 = packbf2(xv2.y, xv2.z); u3 = packbf2(xv2.z, xv2.w);
        *reinterpret_cast<uint2*>(&pkw[b2 + 36]) = make_uint2(u0, u1);
        *reinterpret_cast<uint2*>(&pkw[b2 + 38]) = make_uint2(u2, u3);

        const int bx = 976 + y * 54 + (lq << 2);      // px18: pairs (stripe, stripe+18)
        u0 = packbf2(xv0.x, xv1.x); u1 = packbf2(xv0.y, xv1.y);
        u2 = packbf2(xv0.z, xv1.z); u3 = packbf2(xv0.w, xv1.w);
        *reinterpret_cast<uint2*>(&pkw[bx])      = make_uint2(u0, u1);
        *reinterpret_cast<uint2*>(&pkw[bx + 2])  = make_uint2(u2, u3);
        u0 = packbf2(xv1.x, xv2.x); u1 = packbf2(xv1.y, xv2.y);
        u2 = packbf2(xv1.z, xv2.z); u3 = packbf2(xv1.w, xv2.w);
        *reinterpret_cast<uint2*>(&pkw[bx + 18]) = make_uint2(u0, u1);
        *reinterpret_cast<uint2*>(&pkw[bx + 20]) = make_uint2(u2, u3);
        u0 = packbf2(xv2.x, nxx);  u1 = packbf2(xv2.y, nxy);
        u2 = packbf2(xv2.z, nxz);  u3 = packbf2(xv2.w, nxw);
        *reinterpret_cast<uint2*>(&pkw[bx + 36]) = make_uint2(u0, u1);
        *reinterpret_cast<uint2*>(&pkw[bx + 38]) = make_uint2(u2, u3);

        if (lr == 0) {  // px18 halo row 0, c2 stripe pairs with real row-1 c0
            const int b0 = 976 + 36 + (lq << 2);
            u0 = packbf2(0.f, xv0.x); u1 = packbf2(0.f, xv0.y);
            u2 = packbf2(0.f, xv0.z); u3 = packbf2(0.f, xv0.w);
            *reinterpret_cast<uint2*>(&pkw[b0])     = make_uint2(u0, u1);
            *reinterpret_cast<uint2*>(&pkw[b0 + 2]) = make_uint2(u2, u3);
        }
    }
    __builtin_amdgcn_wave_barrier();

    // ---- per-lane pair-read offsets (dwords); +mt*54 in loop, folded to imm ----
    int offp0, offp1, offp2, offp3;
    if (kb < 2) {                       // q0..q7 (kx0,kx1) pairs in p2
        const int t0 = kb * 72 + r16;
        offp0 = t0; offp1 = t0 + 18; offp2 = t0 + 36; offp3 = t0 + 54;
    } else if (kb == 2) {               // q8 pair in p2; q0/q2/q4 kx2 pairs in px18
        offp0 = 144 + r16; offp1 = 977 + r16; offp2 = 1013 + r16; offp3 = 1049 + r16;
    } else {                            // q6,q8 kx2 pairs in px18; slots 28..31 dead
        offp0 = 1085 + r16; offp1 = 1121 + r16; offp2 = 1121 + r16; offp3 = 1121 + r16;
    }

    const f32x4 cbv0 = {cbs0, cbs0, cbs0, cbs0};
    const f32x4 cbv1 = {cbs1, cbs1, cbs1, cbs1};
    const f32x4 cbv2 = {cbs2, cbs2, cbs2, cbs2};
    const f32x4 cbv3 = {cbs3, cbs3, cbs3, cbs3};
    const float rb16 = cbs4 * 16.f;     // router bias: 16 steps fold into C init
    f32x4 a4acc = {rb16, rb16, rb16, rb16};

    // ---- split geometry (wave-uniform) ----
    const int iA = cellOf(rbase), iB = cellOf(rbase + 15);
    const int jA = cellOf(cbase), jB = cellOf(cbase + 15);
    const int isp = (iA + 1) * 66 - 4 - rbase;    // <16 iff i-split
    const int jsp = (jA + 1) * 66 - 4 - cbase;    // <16 iff j-split
    const bool anySplit = (isp < 16) | (jsp < 16);

    const pf2 zz2 = {0.f, 0.f};

    if (!anySplit) {
        // ================= lean path (75% of patches) =================
        pf2 pall2[4] = {zz2, zz2, zz2, zz2};
        pf2 psb2[4]  = {zz2, zz2, zz2, zz2};      // dead (ACCJ=0)
        pf2 jm2lo = zz2, jm2hi = zz2;             // dead
        (void)psb2; (void)jm2lo; (void)jm2hi;
        #pragma unroll
        for (int mt = 0; mt < 16; ++mt) CONV_STEP(mt * 54, 0);

        float rsum = (a4acc[0] + a4acc[1]) + (a4acc[2] + a4acc[3]);
        GATES_FROM_RSUM();

        float tt = 0.f;
        #pragma unroll
        for (int nt = 0; nt < 4; ++nt)
            tt = fmaf(gv[nt], pall2[nt].x + pall2[nt].y, tt);
        tt += __shfl_xor(tt, 8);
        tt += __shfl_xor(tt, 16);
        tt += __shfl_xor(tt, 32);
        if (lid < 8) {
            float4 v = make_float4(tt, 0.f, 0.f, 0.f);
            *reinterpret_cast<float4*>(&Sout[(gp << 5) + (lid << 2)]) = v;
        }
    } else {
        // ================= generic split path =================
        float jmask[4];
        #pragma unroll
        for (int r = 0; r < 4; ++r)
            jmask[r] = ((kb << 2) + r >= jsp) ? 1.f : 0.f;
        const pf2 jm2lo = {jmask[0], jmask[1]};
        const pf2 jm2hi = {jmask[2], jmask[3]};

        pf2 pall2[4] = {zz2, zz2, zz2, zz2};
        pf2 psb2[4]  = {zz2, zz2, zz2, zz2};
        const int m1 = isp < 16 ? isp : 16;

        int sb = 0;
        for (int mt = 0; mt < m1; ++mt) { CONV_STEP(sb, 1); sb += 54; }
        const float pa0_0 = pall2[0].x + pall2[0].y;
        const float pa0_1 = pall2[1].x + pall2[1].y;
        const float pa0_2 = pall2[2].x + pall2[2].y;
        const float pa0_3 = pall2[3].x + pall2[3].y;
        const float pb0_0 = psb2[0].x + psb2[0].y;
        const float pb0_1 = psb2[1].x + psb2[1].y;
        const float pb0_2 = psb2[2].x + psb2[2].y;
        const float pb0_3 = psb2[3].x + psb2[3].y;
        pall2[0] = pall2[1] = pall2[2] = pall2[3] = zz2;
        psb2[0] = psb2[1] = psb2[2] = psb2[3] = zz2;
        for (int mt = m1; mt < 16; ++mt) { CONV_STEP(sb, 1); sb += 54; }

        float rsum = (a4acc[0] + a4acc[1]) + (a4acc[2] + a4acc[3]);
        GATES_FROM_RSUM();

        float tTA = gv[0] * pa0_0 + gv[1] * pa0_1 + gv[2] * pa0_2 + gv[3] * pa0_3;
        float tTB = gv[0] * pb0_0 + gv[1] * pb0_1 + gv[2] * pb0_2 + gv[3] * pb0_3;
        float tBA = 0.f, tBB = 0.f;
        #pragma unroll
        for (int nt = 0; nt < 4; ++nt) {
            tBA = fmaf(gv[nt], pall2[nt].x + pall2[nt].y, tBA);
            tBB = fmaf(gv[nt], psb2[nt].x + psb2[nt].y, tBB);
        }
        #pragma unroll
        for (int m = 8; m <= 32; m <<= 1) {
            tTA += __shfl_xor(tTA, m);
            tTB += __shfl_xor(tTB, m);
            tBA += __shfl_xor(tBA, m);
            tBB += __shfl_xor(tBB, m);
        }
        if (lid < 8) {
            float4 v = make_float4(tTA, tTB, tBA, tBB);
            *reinterpret_cast<float4*>(&Sout[(gp << 5) + (lid << 2)]) = v;
        }
    }
}

// ---------------- reduce Sout + SPP + head ----------------
__global__ __launch_bounds__(256) void head_kernel(
    const float* __restrict__ Sout, const float* __restrict__ fw,
    const float* __restrict__ fb, const float* __restrict__ lw,
    const float* __restrict__ lb, float* __restrict__ out)
{
    __shared__ float syl[128];
    __shared__ float s2[32];
    __shared__ float stot[8];
    __shared__ float spp[168];
    const int t = threadIdx.x;
    const int b = blockIdx.y;

    if (t < 128) syl[t] = 0.f;
    __syncthreads();

    // phase A: reduce Sout[b*256 .. +255][8][4] into syl[c*16+cell].
    // thread t: channel c = t&7, patch group pg = t>>3 (8 patches each);
    // lanes 0..7 share a patch -> their float4 loads are one 128B burst.
    {
        const int c = t & 7;
        const int pg = t >> 3;
        #pragma unroll
        for (int k = 0; k < 8; ++k) {
            const int p = pg * 8 + k;
            const float4 v = *reinterpret_cast<const float4*>(
                &Sout[((b << 8) + p) * 32 + (c << 2)]);
            const int pi = p >> 4, pj = p & 15;
            const int iA = cellOf(pi << 4), iB = cellOf((pi << 4) + 15);
            const int jA = cellOf(pj << 4), jB = cellOf((pj << 4) + 15);
            float* q = &syl[c << 4];
            atomicAdd(&q[iA * 4 + jA], v.x - v.y);
            atomicAdd(&q[iA * 4 + jB], v.y);
            atomicAdd(&q[iB * 4 + jA], v.z - v.w);
            atomicAdd(&q[iB * 4 + jB], v.w);
        }
    }
    __syncthreads();

    if (t < 32) {
        int c = t >> 2, I = (t >> 1) & 1, J = t & 1;
        const float* p = &syl[c * 16];
        s2[t] = p[(2 * I) * 4 + 2 * J] + p[(2 * I) * 4 + 2 * J + 1] +
                p[(2 * I + 1) * 4 + 2 * J] + p[(2 * I + 1) * 4 + 2 * J + 1];
    } else if (t >= 32 && t < 40) {
        int c = t - 32;
        float s = 0.f;
        #pragma unroll
        for (int i2 = 0; i2 < 16; ++i2) s += syl[c * 16 + i2];
        stot[c] = s;
    }
    __syncthreads();
    if (t < 168) {
        float acc = 0.f;
        int o;
        if (t < 8) {
            o = t;
            #pragma unroll
            for (int c = 0; c < 8; ++c) acc += fw[o * 8 + c] * stot[c];
            acc *= (1.f / 69696.f);
        } else if (t < 40) {
            int m = t - 8; o = m >> 2; int q = m & 3;
            #pragma unroll
            for (int c = 0; c < 8; ++c) acc += fw[o * 8 + c] * s2[c * 4 + q];
            acc *= (1.f / 17424.f);
        } else {
            int m = t - 40; o = m >> 4; int cell = m & 15;
            #pragma unroll
            for (int c = 0; c < 8; ++c) acc += fw[o * 8 + c] * syl[c * 16 + cell];
            acc *= (1.f / 4356.f);
        }
        spp[t] = acc + fb[o];
    }
    __syncthreads();
    const int n = blockIdx.x * 256 + t;
    if (n < 1000) {
        float acc = lb[n];
        for (int k = 0; k < 168; ++k) acc = fmaf(spp[k], lw[k * 1000 + n], acc);
        out[b * 1000 + n] = acc;
    }
}

extern "C" void kernel_launch(void* const* d_in, const int* in_sizes, int n_in,
                              void* d_out, int out_size, void* d_ws, size_t ws_size,
                              hipStream_t stream) {
    const float* X    = (const float*)d_in[0];
    const float* ew   = (const float*)d_in[1];
    const float* eb   = (const float*)d_in[2];
    const float* pw   = (const float*)d_in[3];
    const float* pb   = (const float*)d_in[4];
    const float* keys = (const float*)d_in[5];
    const float* thr  = (const float*)d_in[6];
    const float* fw   = (const float*)d_in[7];
    const float* fb   = (const float*)d_in[8];
    const float* lw   = (const float*)d_in[9];
    const float* lb   = (const float*)d_in[10];
    float* out  = (float*)d_out;
    float* Sout = (float*)d_ws;                 // 8192*32 floats = 1MB

    fused_kernel<<<2048, 256, 0, stream>>>(X, ew, eb, pw, pb, keys, thr, Sout);
    head_kernel<<<dim3(4, 32), 256, 0, stream>>>(Sout, fw, fb, lw, lb, out);
}

// Round 10
// 47.485 us; speedup vs baseline: 1.1423x; 1.1423x over previous
//
#include <hip/hip_runtime.h>
#include <hip/hip_bf16.h>
#include <math.h>

// X: [32,3,256,256]; 8192 independent 16x16 patches (conv pad=1 zero-pads per
// patch). One wave = one patch, ZERO block-level syncs in the fused kernel.
//
// v11 = v6 (champion, 37.7us) + three consolidations + setprio:
//  - prep does B+bias ONLY (the 8K-float Sy zero is gone: store-based output
//    needs no zero-init). prep is ~1us of single-block work now.
//  - fused output: each patch stores {tTA,tTB,tBA,tBB} per channel as one
//    coalesced float4 to Sout[patch][8][4] (plain dwordx4, no RMW tail).
//  - head phase A: deterministic per-(channel,cell) gather over the <=5x5
//    patch rectangle overlapping that cell (bounds from 66-row cell geometry),
//    uniform A/B-cell selection formula, NO atomics.
//  - s_setprio(1) around the conv+accumulate region (T5: helps independent
//    per-wave-block kernels; our fused is exactly that regime).
// v6 carried verbatim: packed-f32 relu/accumulate, XCD swizzle, full slab
// zero, pre-packed bf16 PAIR slabs (p2 = pack(v,v+1), px18 = pack(v,v+18));
// B k''-slot order matches; hot loop = 4 aligned ds_read_b32 -> 5 MFMAs;
// bias in MFMA C operands; router accumulator chained through C.

typedef short bf16x8 __attribute__((ext_vector_type(8)));
typedef float f32x4 __attribute__((ext_vector_type(4)));
typedef float pf2 __attribute__((ext_vector_type(2)));

__device__ __forceinline__ int cellOf(int r) {
    int rr = r + 4;   // padded coordinate; cells of 66 in [0,264)
    return (rr >= 66) + (rr >= 132) + (rr >= 198);
}

__device__ __forceinline__ unsigned int packbf2(float lo, float hi) {
    __hip_bfloat162 h = __float22bfloat162_rn(make_float2(lo, hi));
    unsigned int u;
    __builtin_memcpy(&u, &h, 4);
    return u;
}

// ---------------- prep: build packed B + bias vectors (no Sy zero) ----------------
__global__ __launch_bounds__(256) void prep_kernel(
    const float* __restrict__ ew, const float* __restrict__ ebg,
    const float* __restrict__ pw, const float* __restrict__ pb,
    const float* __restrict__ keys,
    unsigned short* __restrict__ Bg, float* __restrict__ cbf)
{
    const int t = threadIdx.x;
    if (t < 72) {
        float sv[32];
        #pragma unroll
        for (int s = 0; s < 32; ++s) {
            int q, kx; bool zz = false;
            if (s < 16)       { q = s >> 1;  kx = s & 1; }
            else if (s < 18)  { q = 8;       kx = s - 16; }
            else if (s < 26)  { q = s - 18;  kx = 2; }
            else if (s == 26) { q = 8;       kx = 2; }
            else              { q = 0; kx = 0; zz = true; }
            const int ky = q / 3, c = q - ky * 3;
            const int widx = c * 9 + ky * 3 + kx;
            float a;
            if (t < 64) {
                a = ew[t * 27 + widx];
            } else {
                const int e = t - 64;
                a = 0.f;
                #pragma unroll
                for (int o = 0; o < 16; ++o)
                    a += keys[e * 16 + o] * pw[o * 27 + widx];
            }
            sv[s] = zz ? 0.f : a;
        }
        uint4 q0, q1, q2v, q3v;
        q0.x  = packbf2(sv[0],  sv[1]);  q0.y  = packbf2(sv[2],  sv[3]);
        q0.z  = packbf2(sv[4],  sv[5]);  q0.w  = packbf2(sv[6],  sv[7]);
        q1.x  = packbf2(sv[8],  sv[9]);  q1.y  = packbf2(sv[10], sv[11]);
        q1.z  = packbf2(sv[12], sv[13]); q1.w  = packbf2(sv[14], sv[15]);
        q2v.x = packbf2(sv[16], sv[17]); q2v.y = packbf2(sv[18], sv[19]);
        q2v.z = packbf2(sv[20], sv[21]); q2v.w = packbf2(sv[22], sv[23]);
        q3v.x = packbf2(sv[24], sv[25]); q3v.y = packbf2(sv[26], sv[27]);
        q3v.z = packbf2(sv[28], sv[29]); q3v.w = packbf2(sv[30], sv[31]);
        uint4* dst = reinterpret_cast<uint4*>(&Bg[t * 32]);
        dst[0] = q0; dst[1] = q1; dst[2] = q2v; dst[3] = q3v;
    }
    // bias vectors: cbf[0..63] = expert bias per channel; cbf[64..79] = router
    // bias per column (col j -> expert j&7)
    if (t >= 128 && t < 208) {
        const int i = t - 128;
        float c;
        if (i < 64) {
            c = ebg[i];
        } else {
            const int e = (i - 64) & 7;
            c = 0.f;
            #pragma unroll
            for (int o = 0; o < 16; ++o) c += keys[e * 16 + o] * pb[o];
        }
        cbf[i] = c;
    }
}

// one conv step: 4 aligned b32 pair-reads, 5 MFMAs, PACKED relu accumulate.
#define CONV_STEP(SB, ACCJ) do {                                            \
    uint4 pkv;                                                              \
    pkv.x = pkw[offp0 + (SB)];                                              \
    pkv.y = pkw[offp1 + (SB)];                                              \
    pkv.z = pkw[offp2 + (SB)];                                              \
    pkv.w = pkw[offp3 + (SB)];                                              \
    const bf16x8 afr = __builtin_bit_cast(bf16x8, pkv);                     \
    const f32x4 a0 = __builtin_amdgcn_mfma_f32_16x16x32_bf16(afr, bfr0, cbv0, 0, 0, 0); \
    const f32x4 a1 = __builtin_amdgcn_mfma_f32_16x16x32_bf16(afr, bfr1, cbv1, 0, 0, 0); \
    const f32x4 a2 = __builtin_amdgcn_mfma_f32_16x16x32_bf16(afr, bfr2, cbv2, 0, 0, 0); \
    const f32x4 a3 = __builtin_amdgcn_mfma_f32_16x16x32_bf16(afr, bfr3, cbv3, 0, 0, 0); \
    a4acc = __builtin_amdgcn_mfma_f32_16x16x32_bf16(afr, bfr4, a4acc, 0, 0, 0); \
    const pf2 z2_ = {0.f, 0.f};                                             \
    {                                                                       \
        const pf2 l_ = __builtin_elementwise_max((pf2)__builtin_shufflevector(a0, a0, 0, 1), z2_); \
        const pf2 h_ = __builtin_elementwise_max((pf2)__builtin_shufflevector(a0, a0, 2, 3), z2_); \
        pall2[0] += l_ + h_;                                                \
        if (ACCJ) psb2[0] += l_ * jm2lo + h_ * jm2hi;                       \
    }                                                                       \
    {                                                                       \
        const pf2 l_ = __builtin_elementwise_max((pf2)__builtin_shufflevector(a1, a1, 0, 1), z2_); \
        const pf2 h_ = __builtin_elementwise_max((pf2)__builtin_shufflevector(a1, a1, 2, 3), z2_); \
        pall2[1] += l_ + h_;                                                \
        if (ACCJ) psb2[1] += l_ * jm2lo + h_ * jm2hi;                       \
    }                                                                       \
    {                                                                       \
        const pf2 l_ = __builtin_elementwise_max((pf2)__builtin_shufflevector(a2, a2, 0, 1), z2_); \
        const pf2 h_ = __builtin_elementwise_max((pf2)__builtin_shufflevector(a2, a2, 2, 3), z2_); \
        pall2[2] += l_ + h_;                                                \
        if (ACCJ) psb2[2] += l_ * jm2lo + h_ * jm2hi;                       \
    }                                                                       \
    {                                                                       \
        const pf2 l_ = __builtin_elementwise_max((pf2)__builtin_shufflevector(a3, a3, 0, 1), z2_); \
        const pf2 h_ = __builtin_elementwise_max((pf2)__builtin_shufflevector(a3, a3, 2, 3), z2_); \
        pall2[3] += l_ + h_;                                                \
        if (ACCJ) psb2[3] += l_ * jm2lo + h_ * jm2hi;                       \
    }                                                                       \
} while (0)

// softmax + gate (all 64 lanes; lane's expert e = lid&7)
#define GATES_FROM_RSUM()                                                   \
    rsum += __shfl_xor(rsum, 16);                                           \
    rsum += __shfl_xor(rsum, 32);                                           \
    float gv[4];                                                            \
    {                                                                       \
        float lg = rsum * (1.f / 256.f);                                    \
        float mx = fmaxf(lg, __shfl_xor(lg, 1));                            \
        mx = fmaxf(mx, __shfl_xor(mx, 2));                                  \
        mx = fmaxf(mx, __shfl_xor(mx, 4));                                  \
        float ex = __expf(lg - mx);                                         \
        float s = ex;                                                       \
        s += __shfl_xor(s, 1); s += __shfl_xor(s, 2); s += __shfl_xor(s, 4);\
        float sc = ex / s;                                                  \
        float g = sc / (1.f + __expf(-(sc - thr) * 10.f));                  \
        float gs = g;                                                       \
        gs += __shfl_xor(gs, 1); gs += __shfl_xor(gs, 2); gs += __shfl_xor(gs, 4); \
        float gn = g / (gs + 1e-9f);                                        \
        const int gb = (lid & 56);                                          \
        const int hb = (lid >> 3) & 1;                                      \
        gv[0] = __shfl(gn, gb | (0 + hb));                                  \
        gv[1] = __shfl(gn, gb | (2 + hb));                                  \
        gv[2] = __shfl(gn, gb | (4 + hb));                                  \
        gv[3] = __shfl(gn, gb | (6 + hb));                                  \
    }

// ---------------- fused expert+router conv, store-based output ----------------
__global__ __launch_bounds__(256, 4) void fused_kernel(
    const float* __restrict__ X, const unsigned short* __restrict__ Bg,
    const float* __restrict__ thr_p, const float* __restrict__ cbf,
    float* __restrict__ Sout)
{
    // per-wave packed pair slabs: p2 at [0..976), px18 stored at 976+i
    __shared__ __align__(16) unsigned int pk[4][1952];

    const int t = threadIdx.x;
    const int wid = t >> 6, lid = t & 63;
    const int r16 = lid & 15, kb = lid >> 4;

    // XCD swizzle: all 64 blocks of one image land on one XCD (2048%8==0)
    const int wgid = blockIdx.x;
    const int virt = (wgid & 7) * 256 + (wgid >> 3);

    const int gp = (virt << 2) + wid;             // patch id 0..8191
    const int b = gp >> 8;
    const int pi = (gp >> 4) & 15, pj = gp & 15;
    const int rbase = pi << 4, cbase = pj << 4;

    unsigned int* pkw = pk[wid];
    const float thr = thr_p[0];

    // ---- issue all global loads up front (in flight together) ----
    const int lr = lid >> 2, lq = lid & 3;
    const float* xb = X + ((b * 3) << 16) + ((rbase + lr) << 8) + cbase + (lq << 2);
    const float4 xv0 = *reinterpret_cast<const float4*>(xb);
    const float4 xv1 = *reinterpret_cast<const float4*>(xb + 65536);
    const float4 xv2 = *reinterpret_cast<const float4*>(xb + 131072);

    const bf16x8 bfr0 = *reinterpret_cast<const bf16x8*>(&Bg[(r16) * 32 + (kb << 3)]);
    const bf16x8 bfr1 = *reinterpret_cast<const bf16x8*>(&Bg[(16 + r16) * 32 + (kb << 3)]);
    const bf16x8 bfr2 = *reinterpret_cast<const bf16x8*>(&Bg[(32 + r16) * 32 + (kb << 3)]);
    const bf16x8 bfr3 = *reinterpret_cast<const bf16x8*>(&Bg[(48 + r16) * 32 + (kb << 3)]);
    const bf16x8 bfr4 = *reinterpret_cast<const bf16x8*>(&Bg[(64 + (r16 & 7)) * 32 + (kb << 3)]);

    const float cbs0 = cbf[r16];
    const float cbs1 = cbf[16 + r16];
    const float cbs2 = cbf[32 + r16];
    const float cbs3 = cbf[48 + r16];
    const float cbs4 = cbf[64 + r16];

    // ---- zero the packed region (covers halo rows/cols; wave-private) ----
    {
        uint4* pk4 = reinterpret_cast<uint4*>(pkw);
        const uint4 z = make_uint4(0u, 0u, 0u, 0u);
        #pragma unroll
        for (int i = 0; i < 8; ++i) {
            const int idx = lid + (i << 6);
            if (idx < 488) pk4[idx] = z;
        }
    }
    __builtin_amdgcn_wave_barrier();

    // ---- build packed pair slabs straight from registers ----
    // lane owns input row lr (slab y = lr+1), slab cols 4lq+1..4lq+4, 3 chans.
    float s0 = __shfl_up(xv0.w, 1);
    float s1 = __shfl_up(xv1.w, 1);
    float s2 = __shfl_up(xv2.w, 1);
    const float c0p = (lq == 0) ? 0.f : s0;   // col 4lq (left neighbor / halo)
    const float c1p = (lq == 0) ? 0.f : s1;
    const float c2p = (lq == 0) ? 0.f : s2;
    float nxx = __shfl_down(xv0.x, 4);        // next row, channel 0 (for px c2)
    float nxy = __shfl_down(xv0.y, 4);
    float nxz = __shfl_down(xv0.z, 4);
    float nxw = __shfl_down(xv0.w, 4);
    if (lr == 15) { nxx = 0.f; nxy = 0.f; nxz = 0.f; nxw = 0.f; }

    {
        const int y = lr + 1;
        const int b2 = y * 54 + (lq << 2);            // p2: pairs (col p, col p+1)
        unsigned int u0, u1, u2, u3;
        u0 = packbf2(c0p,   xv0.x); u1 = packbf2(xv0.x, xv0.y);
        u2 = packbf2(xv0.y, xv0.z); u3 = packbf2(xv0.z, xv0.w);
        *reinterpret_cast<uint2*>(&pkw[b2])      = make_uint2(u0, u1);
        *reinterpret_cast<uint2*>(&pkw[b2 + 2])  = make_uint2(u2, u3);
        u0 = packbf2(c1p,   xv1.x); u1 = packbf2(xv1.x, xv1.y);
        u2 = packbf2(xv1.y, xv1.z); u3 = packbf2(xv1.z, xv1.w);
        *reinterpret_cast<uint2*>(&pkw[b2 + 18]) = make_uint2(u0, u1);
        *reinterpret_cast<uint2*>(&pkw[b2 + 20]) = make_uint2(u2, u3);
        u0 = packbf2(c2p,   xv2.x); u1 = packbf2(xv2.x, xv2.y);
        u2 = packbf2(xv2.y, xv2.z); u3 = packbf2(xv2.z, xv2.w);
        *reinterpret_cast<uint2*>(&pkw[b2 + 36]) = make_uint2(u0, u1);
        *reinterpret_cast<uint2*>(&pkw[b2 + 38]) = make_uint2(u2, u3);

        const int bx = 976 + y * 54 + (lq << 2);      // px18: pairs (stripe, stripe+18)
        u0 = packbf2(xv0.x, xv1.x); u1 = packbf2(xv0.y, xv1.y);
        u2 = packbf2(xv0.z, xv1.z); u3 = packbf2(xv0.w, xv1.w);
        *reinterpret_cast<uint2*>(&pkw[bx])      = make_uint2(u0, u1);
        *reinterpret_cast<uint2*>(&pkw[bx + 2])  = make_uint2(u2, u3);
        u0 = packbf2(xv1.x, xv2.x); u1 = packbf2(xv1.y, xv2.y);
        u2 = packbf2(xv1.z, xv2.z); u3 = packbf2(xv1.w, xv2.w);
        *reinterpret_cast<uint2*>(&pkw[bx + 18]) = make_uint2(u0, u1);
        *reinterpret_cast<uint2*>(&pkw[bx + 20]) = make_uint2(u2, u3);
        u0 = packbf2(xv2.x, nxx);  u1 = packbf2(xv2.y, nxy);
        u2 = packbf2(xv2.z, nxz);  u3 = packbf2(xv2.w, nxw);
        *reinterpret_cast<uint2*>(&pkw[bx + 36]) = make_uint2(u0, u1);
        *reinterpret_cast<uint2*>(&pkw[bx + 38]) = make_uint2(u2, u3);

        if (lr == 0) {  // px18 halo row 0, c2 stripe pairs with real row-1 c0
            const int b0 = 976 + 36 + (lq << 2);
            u0 = packbf2(0.f, xv0.x); u1 = packbf2(0.f, xv0.y);
            u2 = packbf2(0.f, xv0.z); u3 = packbf2(0.f, xv0.w);
            *reinterpret_cast<uint2*>(&pkw[b0])     = make_uint2(u0, u1);
            *reinterpret_cast<uint2*>(&pkw[b0 + 2]) = make_uint2(u2, u3);
        }
    }
    __builtin_amdgcn_wave_barrier();

    // ---- per-lane pair-read offsets (dwords); +mt*54 in loop, folded to imm ----
    int offp0, offp1, offp2, offp3;
    if (kb < 2) {                       // q0..q7 (kx0,kx1) pairs in p2
        const int t0 = kb * 72 + r16;
        offp0 = t0; offp1 = t0 + 18; offp2 = t0 + 36; offp3 = t0 + 54;
    } else if (kb == 2) {               // q8 pair in p2; q0/q2/q4 kx2 pairs in px18
        offp0 = 144 + r16; offp1 = 977 + r16; offp2 = 1013 + r16; offp3 = 1049 + r16;
    } else {                            // q6,q8 kx2 pairs in px18; slots 28..31 dead
        offp0 = 1085 + r16; offp1 = 1121 + r16; offp2 = 1121 + r16; offp3 = 1121 + r16;
    }

    const f32x4 cbv0 = {cbs0, cbs0, cbs0, cbs0};
    const f32x4 cbv1 = {cbs1, cbs1, cbs1, cbs1};
    const f32x4 cbv2 = {cbs2, cbs2, cbs2, cbs2};
    const f32x4 cbv3 = {cbs3, cbs3, cbs3, cbs3};
    const float rb16 = cbs4 * 16.f;     // router bias: 16 steps fold into C init
    f32x4 a4acc = {rb16, rb16, rb16, rb16};

    // ---- split geometry (wave-uniform) ----
    const int iA = cellOf(rbase), iB = cellOf(rbase + 15);
    const int jA = cellOf(cbase), jB = cellOf(cbase + 15);
    const int isp = (iA + 1) * 66 - 4 - rbase;    // <16 iff i-split
    const int jsp = (jA + 1) * 66 - 4 - cbase;    // <16 iff j-split
    const bool anySplit = (isp < 16) | (jsp < 16);

    const pf2 zz2 = {0.f, 0.f};

    if (!anySplit) {
        // ================= lean path (75% of patches) =================
        pf2 pall2[4] = {zz2, zz2, zz2, zz2};
        pf2 psb2[4]  = {zz2, zz2, zz2, zz2};      // dead (ACCJ=0)
        pf2 jm2lo = zz2, jm2hi = zz2;             // dead
        (void)psb2; (void)jm2lo; (void)jm2hi;
        __builtin_amdgcn_s_setprio(1);
        #pragma unroll
        for (int mt = 0; mt < 16; ++mt) CONV_STEP(mt * 54, 0);
        __builtin_amdgcn_s_setprio(0);

        float rsum = (a4acc[0] + a4acc[1]) + (a4acc[2] + a4acc[3]);
        GATES_FROM_RSUM();

        float tt = 0.f;
        #pragma unroll
        for (int nt = 0; nt < 4; ++nt)
            tt = fmaf(gv[nt], pall2[nt].x + pall2[nt].y, tt);
        tt += __shfl_xor(tt, 8);
        tt += __shfl_xor(tt, 16);
        tt += __shfl_xor(tt, 32);
        if (lid < 8) {
            float4 v = make_float4(tt, 0.f, 0.f, 0.f);
            *reinterpret_cast<float4*>(&Sout[(gp << 5) + (lid << 2)]) = v;
        }
    } else {
        // ================= generic split path =================
        float jmask[4];
        #pragma unroll
        for (int r = 0; r < 4; ++r)
            jmask[r] = ((kb << 2) + r >= jsp) ? 1.f : 0.f;
        const pf2 jm2lo = {jmask[0], jmask[1]};
        const pf2 jm2hi = {jmask[2], jmask[3]};

        pf2 pall2[4] = {zz2, zz2, zz2, zz2};
        pf2 psb2[4]  = {zz2, zz2, zz2, zz2};
        const int m1 = isp < 16 ? isp : 16;

        __builtin_amdgcn_s_setprio(1);
        int sb = 0;
        for (int mt = 0; mt < m1; ++mt) { CONV_STEP(sb, 1); sb += 54; }
        const float pa0_0 = pall2[0].x + pall2[0].y;
        const float pa0_1 = pall2[1].x + pall2[1].y;
        const float pa0_2 = pall2[2].x + pall2[2].y;
        const float pa0_3 = pall2[3].x + pall2[3].y;
        const float pb0_0 = psb2[0].x + psb2[0].y;
        const float pb0_1 = psb2[1].x + psb2[1].y;
        const float pb0_2 = psb2[2].x + psb2[2].y;
        const float pb0_3 = psb2[3].x + psb2[3].y;
        pall2[0] = pall2[1] = pall2[2] = pall2[3] = zz2;
        psb2[0] = psb2[1] = psb2[2] = psb2[3] = zz2;
        for (int mt = m1; mt < 16; ++mt) { CONV_STEP(sb, 1); sb += 54; }
        __builtin_amdgcn_s_setprio(0);

        float rsum = (a4acc[0] + a4acc[1]) + (a4acc[2] + a4acc[3]);
        GATES_FROM_RSUM();

        float tTA = gv[0] * pa0_0 + gv[1] * pa0_1 + gv[2] * pa0_2 + gv[3] * pa0_3;
        float tTB = gv[0] * pb0_0 + gv[1] * pb0_1 + gv[2] * pb0_2 + gv[3] * pb0_3;
        float tBA = 0.f, tBB = 0.f;
        #pragma unroll
        for (int nt = 0; nt < 4; ++nt) {
            tBA = fmaf(gv[nt], pall2[nt].x + pall2[nt].y, tBA);
            tBB = fmaf(gv[nt], psb2[nt].x + psb2[nt].y, tBB);
        }
        #pragma unroll
        for (int m = 8; m <= 32; m <<= 1) {
            tTA += __shfl_xor(tTA, m);
            tTB += __shfl_xor(tTB, m);
            tBA += __shfl_xor(tBA, m);
            tBB += __shfl_xor(tBB, m);
        }
        if (lid < 8) {
            float4 v = make_float4(tTA, tTB, tBA, tBB);
            *reinterpret_cast<float4*>(&Sout[(gp << 5) + (lid << 2)]) = v;
        }
    }
}

// ---------------- reduce Sout + SPP + head ----------------
__global__ __launch_bounds__(256) void head_kernel(
    const float* __restrict__ Sout, const float* __restrict__ fw,
    const float* __restrict__ fb, const float* __restrict__ lw,
    const float* __restrict__ lb, float* __restrict__ out)
{
    __shared__ float syl[128];
    __shared__ float s2[32];
    __shared__ float stot[8];
    __shared__ float spp[168];
    const int t = threadIdx.x;
    const int b = blockIdx.y;

    // phase A: deterministic gather. thread t<128 owns (channel c, cell).
    // Patch p=(pi,pj) contributes to cell (ci,cj) per the A/B split formula:
    //   (iA,jA)+=x-y; (iA,jB)+=y; (iB,jA)+=z-w; (iB,jB)+=w
    // (lean patches store x=tt, y=z=w=0 and have iA==iB, jA==jB).
    if (t < 128) {
        const int c = t & 7;
        const int cell = t >> 3;            // 0..15
        const int ci = cell >> 2, cj = cell & 3;
        // patch index ranges overlapping cell rows/cols (66-cell geometry)
        const int piLo = (ci == 0) ? 0 : (66 * ci - 4) / 16;
        const int piHi = min(15, (66 * ci + 61) / 16);
        const int pjLo = (cj == 0) ? 0 : (66 * cj - 4) / 16;
        const int pjHi = min(15, (66 * cj + 61) / 16);
        float acc = 0.f;
        for (int pi = piLo; pi <= piHi; ++pi) {
            const int iA = cellOf(pi << 4), iB = cellOf((pi << 4) + 15);
            const bool ia = (iA == ci), ib = (iB == ci);
            for (int pj = pjLo; pj <= pjHi; ++pj) {
                const int jA = cellOf(pj << 4), jB = cellOf((pj << 4) + 15);
                const int p = (pi << 4) | pj;
                const float4 v = *reinterpret_cast<const float4*>(
                    &Sout[(((b << 8) + p) << 5) + (c << 2)]);
                float val = 0.f;
                if (ia) {
                    if (jA == cj) val += v.x - v.y;
                    if (jB == cj) val += v.y;
                }
                if (ib) {
                    if (jA == cj) val += v.z - v.w;
                    if (jB == cj) val += v.w;
                }
                acc += val;
            }
        }
        syl[c * 16 + cell] = acc;
    }
    __syncthreads();

    if (t < 32) {
        int c = t >> 2, I = (t >> 1) & 1, J = t & 1;
        const float* p = &syl[c * 16];
        s2[t] = p[(2 * I) * 4 + 2 * J] + p[(2 * I) * 4 + 2 * J + 1] +
                p[(2 * I + 1) * 4 + 2 * J] + p[(2 * I + 1) * 4 + 2 * J + 1];
    } else if (t >= 32 && t < 40) {
        int c = t - 32;
        float s = 0.f;
        #pragma unroll
        for (int i2 = 0; i2 < 16; ++i2) s += syl[c * 16 + i2];
        stot[c] = s;
    }
    __syncthreads();
    if (t < 168) {
        float acc = 0.f;
        int o;
        if (t < 8) {
            o = t;
            #pragma unroll
            for (int c = 0; c < 8; ++c) acc += fw[o * 8 + c] * stot[c];
            acc *= (1.f / 69696.f);
        } else if (t < 40) {
            int m = t - 8; o = m >> 2; int q = m & 3;
            #pragma unroll
            for (int c = 0; c < 8; ++c) acc += fw[o * 8 + c] * s2[c * 4 + q];
            acc *= (1.f / 17424.f);
        } else {
            int m = t - 40; o = m >> 4; int cell = m & 15;
            #pragma unroll
            for (int c = 0; c < 8; ++c) acc += fw[o * 8 + c] * syl[c * 16 + cell];
            acc *= (1.f / 4356.f);
        }
        spp[t] = acc + fb[o];
    }
    __syncthreads();
    const int n = blockIdx.x * 256 + t;
    if (n < 1000) {
        float acc = lb[n];
        for (int k = 0; k < 168; ++k) acc = fmaf(spp[k], lw[k * 1000 + n], acc);
        out[b * 1000 + n] = acc;
    }
}

extern "C" void kernel_launch(void* const* d_in, const int* in_sizes, int n_in,
                              void* d_out, int out_size, void* d_ws, size_t ws_size,
                              hipStream_t stream) {
    const float* X    = (const float*)d_in[0];
    const float* ew   = (const float*)d_in[1];
    const float* eb   = (const float*)d_in[2];
    const float* pw   = (const float*)d_in[3];
    const float* pb   = (const float*)d_in[4];
    const float* keys = (const float*)d_in[5];
    const float* thr  = (const float*)d_in[6];
    const float* fw   = (const float*)d_in[7];
    const float* fb   = (const float*)d_in[8];
    const float* lw   = (const float*)d_in[9];
    const float* lb   = (const float*)d_in[10];
    float* out  = (float*)d_out;
    float* Sout = (float*)d_ws;                                      // 8192*32 floats = 1MB
    unsigned short* Bg = (unsigned short*)((float*)d_ws + 262144);   // 72*32 bf16
    float* cbf = (float*)d_ws + 262144 + 1152;                       // 80 bias floats

    prep_kernel<<<1, 256, 0, stream>>>(ew, eb, pw, pb, keys, Bg, cbf);
    fused_kernel<<<2048, 256, 0, stream>>>(X, Bg, thr, cbf, Sout);
    head_kernel<<<dim3(4, 32), 256, 0, stream>>>(Sout, fw, fb, lw, lb, out);
}

// Round 12
// 37.600 us; speedup vs baseline: 1.4426x; 1.2629x over previous
//
#include <hip/hip_runtime.h>
#include <hip/hip_bf16.h>
#include <math.h>

// X: [32,3,256,256]; 8192 independent 16x16 patches (conv pad=1 zero-pads per
// patch). One wave = one patch, ZERO block-level syncs in the fused kernel.
//
// v12 = v6 verbatim (session champion, 37.7us; 27% below session baseline).
// (Round 11 submission of this exact source failed on an unresponsive
// container -- infra, not kernel. Resubmitting unchanged.)
// Session falsification ledger (kept so future sessions don't re-test):
//  - Sy atomic LINE CONTENTION was the big lever: transposed SyT[cell][b][16]
//    (one 64B line per (cell,b), coalesced 8-lane atomics) won -11us (v5).
//  - Neutral (+-1.5us): VALU-issue cuts (v2/v6), LDS-latency batching (v8),
//    atomic slot-splitting (v8), occupancy quantum 2-wave blocks (v7),
//    persistent grid + cross-patch prefetch (v9), RMW->store output (v10).
//  - Regressions: runtime-indexed reg arrays spill to scratch (v3, rule #20);
//    2-waves-per-patch doubles atomics (v4); in-block B build serializes
//    ~1-2K cy/block (v10); head gather with serial global loads (v11).
//  - Remaining fused time (~28-30us) is a dependency-stall plateau of the
//    one-wave-per-patch decomposition: all pipes <45%, ~10x issue floor,
//    not attributable to any single counter. Next lever would be a
//    different decomposition (in-wave multi-patch ILP interleave).
//
// v6 structure: packed-f32 relu/accumulate (pk_max/pk_add), XCD swizzle,
// transposed SyT, pre-packed bf16 PAIR slabs (p2 = pack(v,v+1), px18 =
// pack(v,v+18)); B k''-slot order matches (built in prep); hot loop =
// 4 aligned ds_read_b32 -> 5 MFMAs; bias in MFMA C operands; router
// accumulator chained through C.

typedef short bf16x8 __attribute__((ext_vector_type(8)));
typedef float f32x4 __attribute__((ext_vector_type(4)));
typedef float pf2 __attribute__((ext_vector_type(2)));

__device__ __forceinline__ int cellOf(int r) {
    int rr = r + 4;   // padded coordinate; cells of 66 in [0,264)
    return (rr >= 66) + (rr >= 132) + (rr >= 198);
}

__device__ __forceinline__ unsigned int packbf2(float lo, float hi) {
    __hip_bfloat162 h = __float22bfloat162_rn(make_float2(lo, hi));
    unsigned int u;
    __builtin_memcpy(&u, &h, 4);
    return u;
}

// ---------------- prep: zero SyT + build packed B + bias vectors ----------------
__global__ __launch_bounds__(256) void prep_kernel(
    const float* __restrict__ ew, const float* __restrict__ ebg,
    const float* __restrict__ pw, const float* __restrict__ pb,
    const float* __restrict__ keys, float* __restrict__ Sy,
    unsigned short* __restrict__ Bg, float* __restrict__ cbf)
{
    const int t = threadIdx.x;
    for (int i = t; i < 8192; i += 256) Sy[i] = 0.f;
    if (t < 72) {
        float sv[32];
        #pragma unroll
        for (int s = 0; s < 32; ++s) {
            int q, kx; bool zz = false;
            if (s < 16)       { q = s >> 1;  kx = s & 1; }
            else if (s < 18)  { q = 8;       kx = s - 16; }
            else if (s < 26)  { q = s - 18;  kx = 2; }
            else if (s == 26) { q = 8;       kx = 2; }
            else              { q = 0; kx = 0; zz = true; }
            const int ky = q / 3, c = q - ky * 3;
            const int widx = c * 9 + ky * 3 + kx;
            float a;
            if (t < 64) {
                a = ew[t * 27 + widx];
            } else {
                const int e = t - 64;
                a = 0.f;
                #pragma unroll
                for (int o = 0; o < 16; ++o)
                    a += keys[e * 16 + o] * pw[o * 27 + widx];
            }
            sv[s] = zz ? 0.f : a;
        }
        uint4 q0, q1, q2v, q3v;
        q0.x  = packbf2(sv[0],  sv[1]);  q0.y  = packbf2(sv[2],  sv[3]);
        q0.z  = packbf2(sv[4],  sv[5]);  q0.w  = packbf2(sv[6],  sv[7]);
        q1.x  = packbf2(sv[8],  sv[9]);  q1.y  = packbf2(sv[10], sv[11]);
        q1.z  = packbf2(sv[12], sv[13]); q1.w  = packbf2(sv[14], sv[15]);
        q2v.x = packbf2(sv[16], sv[17]); q2v.y = packbf2(sv[18], sv[19]);
        q2v.z = packbf2(sv[20], sv[21]); q2v.w = packbf2(sv[22], sv[23]);
        q3v.x = packbf2(sv[24], sv[25]); q3v.y = packbf2(sv[26], sv[27]);
        q3v.z = packbf2(sv[28], sv[29]); q3v.w = packbf2(sv[30], sv[31]);
        uint4* dst = reinterpret_cast<uint4*>(&Bg[t * 32]);
        dst[0] = q0; dst[1] = q1; dst[2] = q2v; dst[3] = q3v;
    }
    // bias vectors: cbf[0..63] = expert bias per channel; cbf[64..79] = router
    // bias per column (col j -> expert j&7)
    if (t >= 128 && t < 208) {
        const int i = t - 128;
        float c;
        if (i < 64) {
            c = ebg[i];
        } else {
            const int e = (i - 64) & 7;
            c = 0.f;
            #pragma unroll
            for (int o = 0; o < 16; ++o) c += keys[e * 16 + o] * pb[o];
        }
        cbf[i] = c;
    }
}

// one conv step: 4 aligned b32 pair-reads, 5 MFMAs, PACKED relu accumulate.
// pall2[n] (f32x2) accumulates relu over regs; psb2[n] adds jmask-weighted
// (jm2lo = {jmask0,jmask1}, jm2hi = {jmask2,jmask3}); pk_fma via contraction.
#define CONV_STEP(SB, ACCJ) do {                                            \
    uint4 pkv;                                                              \
    pkv.x = pkw[offp0 + (SB)];                                              \
    pkv.y = pkw[offp1 + (SB)];                                              \
    pkv.z = pkw[offp2 + (SB)];                                              \
    pkv.w = pkw[offp3 + (SB)];                                              \
    const bf16x8 afr = __builtin_bit_cast(bf16x8, pkv);                     \
    const f32x4 a0 = __builtin_amdgcn_mfma_f32_16x16x32_bf16(afr, bfr0, cbv0, 0, 0, 0); \
    const f32x4 a1 = __builtin_amdgcn_mfma_f32_16x16x32_bf16(afr, bfr1, cbv1, 0, 0, 0); \
    const f32x4 a2 = __builtin_amdgcn_mfma_f32_16x16x32_bf16(afr, bfr2, cbv2, 0, 0, 0); \
    const f32x4 a3 = __builtin_amdgcn_mfma_f32_16x16x32_bf16(afr, bfr3, cbv3, 0, 0, 0); \
    a4acc = __builtin_amdgcn_mfma_f32_16x16x32_bf16(afr, bfr4, a4acc, 0, 0, 0); \
    const pf2 z2_ = {0.f, 0.f};                                             \
    {                                                                       \
        const pf2 l_ = __builtin_elementwise_max((pf2)__builtin_shufflevector(a0, a0, 0, 1), z2_); \
        const pf2 h_ = __builtin_elementwise_max((pf2)__builtin_shufflevector(a0, a0, 2, 3), z2_); \
        pall2[0] += l_ + h_;                                                \
        if (ACCJ) psb2[0] += l_ * jm2lo + h_ * jm2hi;                       \
    }                                                                       \
    {                                                                       \
        const pf2 l_ = __builtin_elementwise_max((pf2)__builtin_shufflevector(a1, a1, 0, 1), z2_); \
        const pf2 h_ = __builtin_elementwise_max((pf2)__builtin_shufflevector(a1, a1, 2, 3), z2_); \
        pall2[1] += l_ + h_;                                                \
        if (ACCJ) psb2[1] += l_ * jm2lo + h_ * jm2hi;                       \
    }                                                                       \
    {                                                                       \
        const pf2 l_ = __builtin_elementwise_max((pf2)__builtin_shufflevector(a2, a2, 0, 1), z2_); \
        const pf2 h_ = __builtin_elementwise_max((pf2)__builtin_shufflevector(a2, a2, 2, 3), z2_); \
        pall2[2] += l_ + h_;                                                \
        if (ACCJ) psb2[2] += l_ * jm2lo + h_ * jm2hi;                       \
    }                                                                       \
    {                                                                       \
        const pf2 l_ = __builtin_elementwise_max((pf2)__builtin_shufflevector(a3, a3, 0, 1), z2_); \
        const pf2 h_ = __builtin_elementwise_max((pf2)__builtin_shufflevector(a3, a3, 2, 3), z2_); \
        pall2[3] += l_ + h_;                                                \
        if (ACCJ) psb2[3] += l_ * jm2lo + h_ * jm2hi;                       \
    }                                                                       \
} while (0)

// softmax + gate (all 64 lanes; lane's expert e = lid&7)
#define GATES_FROM_RSUM()                                                   \
    rsum += __shfl_xor(rsum, 16);                                           \
    rsum += __shfl_xor(rsum, 32);                                           \
    float gv[4];                                                            \
    {                                                                       \
        float lg = rsum * (1.f / 256.f);                                    \
        float mx = fmaxf(lg, __shfl_xor(lg, 1));                            \
        mx = fmaxf(mx, __shfl_xor(mx, 2));                                  \
        mx = fmaxf(mx, __shfl_xor(mx, 4));                                  \
        float ex = __expf(lg - mx);                                         \
        float s = ex;                                                       \
        s += __shfl_xor(s, 1); s += __shfl_xor(s, 2); s += __shfl_xor(s, 4);\
        float sc = ex / s;                                                  \
        float g = sc / (1.f + __expf(-(sc - thr) * 10.f));                  \
        float gs = g;                                                       \
        gs += __shfl_xor(gs, 1); gs += __shfl_xor(gs, 2); gs += __shfl_xor(gs, 4); \
        float gn = g / (gs + 1e-9f);                                        \
        const int gb = (lid & 56);                                          \
        const int hb = (lid >> 3) & 1;                                      \
        gv[0] = __shfl(gn, gb | (0 + hb));                                  \
        gv[1] = __shfl(gn, gb | (2 + hb));                                  \
        gv[2] = __shfl(gn, gb | (4 + hb));                                  \
        gv[3] = __shfl(gn, gb | (6 + hb));                                  \
    }

// ---------------- fused expert+router conv + cell reduce ----------------
__global__ __launch_bounds__(256, 4) void fused_kernel(
    const float* __restrict__ X, const unsigned short* __restrict__ Bg,
    const float* __restrict__ thr_p, const float* __restrict__ cbf,
    float* __restrict__ Sy)
{
    // per-wave packed pair slabs: p2 at [0..976), px18 stored at 976+i
    __shared__ __align__(16) unsigned int pk[4][1952];

    const int t = threadIdx.x;
    const int wid = t >> 6, lid = t & 63;
    const int r16 = lid & 15, kb = lid >> 4;

    // XCD swizzle: all 64 blocks of one image land on one XCD (2048%8==0)
    const int wgid = blockIdx.x;
    const int virt = (wgid & 7) * 256 + (wgid >> 3);

    const int gp = (virt << 2) + wid;             // patch id 0..8191
    const int b = gp >> 8;
    const int pi = (gp >> 4) & 15, pj = gp & 15;
    const int rbase = pi << 4, cbase = pj << 4;

    unsigned int* pkw = pk[wid];
    const float thr = thr_p[0];

    // ---- issue all global loads up front (in flight together) ----
    const int lr = lid >> 2, lq = lid & 3;
    const float* xb = X + ((b * 3) << 16) + ((rbase + lr) << 8) + cbase + (lq << 2);
    const float4 xv0 = *reinterpret_cast<const float4*>(xb);
    const float4 xv1 = *reinterpret_cast<const float4*>(xb + 65536);
    const float4 xv2 = *reinterpret_cast<const float4*>(xb + 131072);

    const bf16x8 bfr0 = *reinterpret_cast<const bf16x8*>(&Bg[(r16) * 32 + (kb << 3)]);
    const bf16x8 bfr1 = *reinterpret_cast<const bf16x8*>(&Bg[(16 + r16) * 32 + (kb << 3)]);
    const bf16x8 bfr2 = *reinterpret_cast<const bf16x8*>(&Bg[(32 + r16) * 32 + (kb << 3)]);
    const bf16x8 bfr3 = *reinterpret_cast<const bf16x8*>(&Bg[(48 + r16) * 32 + (kb << 3)]);
    const bf16x8 bfr4 = *reinterpret_cast<const bf16x8*>(&Bg[(64 + (r16 & 7)) * 32 + (kb << 3)]);

    const float cbs0 = cbf[r16];
    const float cbs1 = cbf[16 + r16];
    const float cbs2 = cbf[32 + r16];
    const float cbs3 = cbf[48 + r16];
    const float cbs4 = cbf[64 + r16];

    // ---- zero the packed region (covers halo rows/cols; wave-private) ----
    {
        uint4* pk4 = reinterpret_cast<uint4*>(pkw);
        const uint4 z = make_uint4(0u, 0u, 0u, 0u);
        #pragma unroll
        for (int i = 0; i < 8; ++i) {
            const int idx = lid + (i << 6);
            if (idx < 488) pk4[idx] = z;
        }
    }
    __builtin_amdgcn_wave_barrier();

    // ---- build packed pair slabs straight from registers ----
    // lane owns input row lr (slab y = lr+1), slab cols 4lq+1..4lq+4, 3 chans.
    float s0 = __shfl_up(xv0.w, 1);
    float s1 = __shfl_up(xv1.w, 1);
    float s2 = __shfl_up(xv2.w, 1);
    const float c0p = (lq == 0) ? 0.f : s0;   // col 4lq (left neighbor / halo)
    const float c1p = (lq == 0) ? 0.f : s1;
    const float c2p = (lq == 0) ? 0.f : s2;
    float nxx = __shfl_down(xv0.x, 4);        // next row, channel 0 (for px c2)
    float nxy = __shfl_down(xv0.y, 4);
    float nxz = __shfl_down(xv0.z, 4);
    float nxw = __shfl_down(xv0.w, 4);
    if (lr == 15) { nxx = 0.f; nxy = 0.f; nxz = 0.f; nxw = 0.f; }

    {
        const int y = lr + 1;
        const int b2 = y * 54 + (lq << 2);            // p2: pairs (col p, col p+1)
        unsigned int u0, u1, u2, u3;
        u0 = packbf2(c0p,   xv0.x); u1 = packbf2(xv0.x, xv0.y);
        u2 = packbf2(xv0.y, xv0.z); u3 = packbf2(xv0.z, xv0.w);
        *reinterpret_cast<uint2*>(&pkw[b2])      = make_uint2(u0, u1);
        *reinterpret_cast<uint2*>(&pkw[b2 + 2])  = make_uint2(u2, u3);
        u0 = packbf2(c1p,   xv1.x); u1 = packbf2(xv1.x, xv1.y);
        u2 = packbf2(xv1.y, xv1.z); u3 = packbf2(xv1.z, xv1.w);
        *reinterpret_cast<uint2*>(&pkw[b2 + 18]) = make_uint2(u0, u1);
        *reinterpret_cast<uint2*>(&pkw[b2 + 20]) = make_uint2(u2, u3);
        u0 = packbf2(c2p,   xv2.x); u1 = packbf2(xv2.x, xv2.y);
        u2 = packbf2(xv2.y, xv2.z); u3 = packbf2(xv2.z, xv2.w);
        *reinterpret_cast<uint2*>(&pkw[b2 + 36]) = make_uint2(u0, u1);
        *reinterpret_cast<uint2*>(&pkw[b2 + 38]) = make_uint2(u2, u3);

        const int bx = 976 + y * 54 + (lq << 2);      // px18: pairs (stripe, stripe+18)
        u0 = packbf2(xv0.x, xv1.x); u1 = packbf2(xv0.y, xv1.y);
        u2 = packbf2(xv0.z, xv1.z); u3 = packbf2(xv0.w, xv1.w);
        *reinterpret_cast<uint2*>(&pkw[bx])      = make_uint2(u0, u1);
        *reinterpret_cast<uint2*>(&pkw[bx + 2])  = make_uint2(u2, u3);
        u0 = packbf2(xv1.x, xv2.x); u1 = packbf2(xv1.y, xv2.y);
        u2 = packbf2(xv1.z, xv2.z); u3 = packbf2(xv1.w, xv2.w);
        *reinterpret_cast<uint2*>(&pkw[bx + 18]) = make_uint2(u0, u1);
        *reinterpret_cast<uint2*>(&pkw[bx + 20]) = make_uint2(u2, u3);
        u0 = packbf2(xv2.x, nxx);  u1 = packbf2(xv2.y, nxy);
        u2 = packbf2(xv2.z, nxz);  u3 = packbf2(xv2.w, nxw);
        *reinterpret_cast<uint2*>(&pkw[bx + 36]) = make_uint2(u0, u1);
        *reinterpret_cast<uint2*>(&pkw[bx + 38]) = make_uint2(u2, u3);

        if (lr == 0) {  // px18 halo row 0, c2 stripe pairs with real row-1 c0
            const int b0 = 976 + 36 + (lq << 2);
            u0 = packbf2(0.f, xv0.x); u1 = packbf2(0.f, xv0.y);
            u2 = packbf2(0.f, xv0.z); u3 = packbf2(0.f, xv0.w);
            *reinterpret_cast<uint2*>(&pkw[b0])     = make_uint2(u0, u1);
            *reinterpret_cast<uint2*>(&pkw[b0 + 2]) = make_uint2(u2, u3);
        }
    }
    __builtin_amdgcn_wave_barrier();

    // ---- per-lane pair-read offsets (dwords); +mt*54 in loop, folded to imm ----
    int offp0, offp1, offp2, offp3;
    if (kb < 2) {                       // q0..q7 (kx0,kx1) pairs in p2
        const int t0 = kb * 72 + r16;
        offp0 = t0; offp1 = t0 + 18; offp2 = t0 + 36; offp3 = t0 + 54;
    } else if (kb == 2) {               // q8 pair in p2; q0/q2/q4 kx2 pairs in px18
        offp0 = 144 + r16; offp1 = 977 + r16; offp2 = 1013 + r16; offp3 = 1049 + r16;
    } else {                            // q6,q8 kx2 pairs in px18; slots 28..31 dead
        offp0 = 1085 + r16; offp1 = 1121 + r16; offp2 = 1121 + r16; offp3 = 1121 + r16;
    }

    const f32x4 cbv0 = {cbs0, cbs0, cbs0, cbs0};
    const f32x4 cbv1 = {cbs1, cbs1, cbs1, cbs1};
    const f32x4 cbv2 = {cbs2, cbs2, cbs2, cbs2};
    const f32x4 cbv3 = {cbs3, cbs3, cbs3, cbs3};
    const float rb16 = cbs4 * 16.f;     // router bias: 16 steps fold into C init
    f32x4 a4acc = {rb16, rb16, rb16, rb16};

    // ---- split geometry (wave-uniform) ----
    const int iA = cellOf(rbase), iB = cellOf(rbase + 15);
    const int jA = cellOf(cbase), jB = cellOf(cbase + 15);
    const int isp = (iA + 1) * 66 - 4 - rbase;    // <16 iff i-split
    const int jsp = (jA + 1) * 66 - 4 - cbase;    // <16 iff j-split
    const bool anySplit = (isp < 16) | (jsp < 16);

    const int bc16 = b << 4;            // SyT[cell][b][16]: line-sized groups
    const pf2 zz2 = {0.f, 0.f};

    if (!anySplit) {
        // ================= lean path (75% of patches) =================
        pf2 pall2[4] = {zz2, zz2, zz2, zz2};
        pf2 psb2[4]  = {zz2, zz2, zz2, zz2};      // dead (ACCJ=0)
        pf2 jm2lo = zz2, jm2hi = zz2;             // dead
        #pragma unroll
        for (int mt = 0; mt < 16; ++mt) CONV_STEP(mt * 54, 0);

        float rsum = (a4acc[0] + a4acc[1]) + (a4acc[2] + a4acc[3]);
        GATES_FROM_RSUM();

        float tt = 0.f;
        #pragma unroll
        for (int nt = 0; nt < 4; ++nt)
            tt = fmaf(gv[nt], pall2[nt].x + pall2[nt].y, tt);
        tt += __shfl_xor(tt, 8);
        tt += __shfl_xor(tt, 16);
        tt += __shfl_xor(tt, 32);
        if (lid < 8)
            atomicAdd(&Sy[(iA * 4 + jA) * 512 + bc16 + lid], tt);
    } else {
        // ================= generic split path =================
        float jmask[4];
        #pragma unroll
        for (int r = 0; r < 4; ++r)
            jmask[r] = ((kb << 2) + r >= jsp) ? 1.f : 0.f;
        const pf2 jm2lo = {jmask[0], jmask[1]};
        const pf2 jm2hi = {jmask[2], jmask[3]};

        pf2 pall2[4] = {zz2, zz2, zz2, zz2};
        pf2 psb2[4]  = {zz2, zz2, zz2, zz2};
        const int m1 = isp < 16 ? isp : 16;

        int sb = 0;
        for (int mt = 0; mt < m1; ++mt) { CONV_STEP(sb, 1); sb += 54; }
        const float pa0_0 = pall2[0].x + pall2[0].y;
        const float pa0_1 = pall2[1].x + pall2[1].y;
        const float pa0_2 = pall2[2].x + pall2[2].y;
        const float pa0_3 = pall2[3].x + pall2[3].y;
        const float pb0_0 = psb2[0].x + psb2[0].y;
        const float pb0_1 = psb2[1].x + psb2[1].y;
        const float pb0_2 = psb2[2].x + psb2[2].y;
        const float pb0_3 = psb2[3].x + psb2[3].y;
        pall2[0] = pall2[1] = pall2[2] = pall2[3] = zz2;
        psb2[0] = psb2[1] = psb2[2] = psb2[3] = zz2;
        for (int mt = m1; mt < 16; ++mt) { CONV_STEP(sb, 1); sb += 54; }

        float rsum = (a4acc[0] + a4acc[1]) + (a4acc[2] + a4acc[3]);
        GATES_FROM_RSUM();

        float tTA = gv[0] * pa0_0 + gv[1] * pa0_1 + gv[2] * pa0_2 + gv[3] * pa0_3;
        float tTB = gv[0] * pb0_0 + gv[1] * pb0_1 + gv[2] * pb0_2 + gv[3] * pb0_3;
        float tBA = 0.f, tBB = 0.f;
        #pragma unroll
        for (int nt = 0; nt < 4; ++nt) {
            tBA = fmaf(gv[nt], pall2[nt].x + pall2[nt].y, tBA);
            tBB = fmaf(gv[nt], psb2[nt].x + psb2[nt].y, tBB);
        }
        #pragma unroll
        for (int m = 8; m <= 32; m <<= 1) {
            tTA += __shfl_xor(tTA, m);
            tTB += __shfl_xor(tTB, m);
            tBA += __shfl_xor(tBA, m);
            tBB += __shfl_xor(tBB, m);
        }
        if (lid < 8) {
            atomicAdd(&Sy[(iA * 4 + jA) * 512 + bc16 + lid], tTA - tTB);
            atomicAdd(&Sy[(iA * 4 + jB) * 512 + bc16 + lid], tTB);
            atomicAdd(&Sy[(iB * 4 + jA) * 512 + bc16 + lid], tBA - tBB);
            atomicAdd(&Sy[(iB * 4 + jB) * 512 + bc16 + lid], tBB);
        }
    }
}

// ---------------- SPP + head ----------------
__global__ __launch_bounds__(256) void head_kernel(
    const float* __restrict__ Sy, const float* __restrict__ fw,
    const float* __restrict__ fb, const float* __restrict__ lw,
    const float* __restrict__ lb, float* __restrict__ out)
{
    __shared__ float syl[128];
    __shared__ float s2[32];
    __shared__ float stot[8];
    __shared__ float spp[168];
    const int t = threadIdx.x;
    const int b = blockIdx.y;
    // SyT[cell][b][16]: syl[c*16+cell] = SyT[cell*512 + b*16 + c]
    if (t < 128) syl[t] = Sy[(t & 15) * 512 + b * 16 + (t >> 4)];
    __syncthreads();
    if (t < 32) {
        int c = t >> 2, I = (t >> 1) & 1, J = t & 1;
        const float* p = &syl[c * 16];
        s2[t] = p[(2 * I) * 4 + 2 * J] + p[(2 * I) * 4 + 2 * J + 1] +
                p[(2 * I + 1) * 4 + 2 * J] + p[(2 * I + 1) * 4 + 2 * J + 1];
    } else if (t >= 32 && t < 40) {
        int c = t - 32;
        float s = 0.f;
        #pragma unroll
        for (int i2 = 0; i2 < 16; ++i2) s += syl[c * 16 + i2];
        stot[c] = s;
    }
    __syncthreads();
    if (t < 168) {
        float acc = 0.f;
        int o;
        if (t < 8) {
            o = t;
            #pragma unroll
            for (int c = 0; c < 8; ++c) acc += fw[o * 8 + c] * stot[c];
            acc *= (1.f / 69696.f);
        } else if (t < 40) {
            int m = t - 8; o = m >> 2; int q = m & 3;
            #pragma unroll
            for (int c = 0; c < 8; ++c) acc += fw[o * 8 + c] * s2[c * 4 + q];
            acc *= (1.f / 17424.f);
        } else {
            int m = t - 40; o = m >> 4; int cell = m & 15;
            #pragma unroll
            for (int c = 0; c < 8; ++c) acc += fw[o * 8 + c] * syl[c * 16 + cell];
            acc *= (1.f / 4356.f);
        }
        spp[t] = acc + fb[o];
    }
    __syncthreads();
    const int n = blockIdx.x * 256 + t;
    if (n < 1000) {
        float acc = lb[n];
        for (int k = 0; k < 168; ++k) acc = fmaf(spp[k], lw[k * 1000 + n], acc);
        out[b * 1000 + n] = acc;
    }
}

extern "C" void kernel_launch(void* const* d_in, const int* in_sizes, int n_in,
                              void* d_out, int out_size, void* d_ws, size_t ws_size,
                              hipStream_t stream) {
    const float* X    = (const float*)d_in[0];
    const float* ew   = (const float*)d_in[1];
    const float* eb   = (const float*)d_in[2];
    const float* pw   = (const float*)d_in[3];
    const float* pb   = (const float*)d_in[4];
    const float* keys = (const float*)d_in[5];
    const float* thr  = (const float*)d_in[6];
    const float* fw   = (const float*)d_in[7];
    const float* fb   = (const float*)d_in[8];
    const float* lw   = (const float*)d_in[9];
    const float* lb   = (const float*)d_in[10];
    float* out = (float*)d_out;
    float* Sy  = (float*)d_ws;                                    // 8192 floats (SyT[16][32][16])
    unsigned short* Bg = (unsigned short*)((float*)d_ws + 8192);  // 72*32 bf16
    float* cbf = (float*)d_ws + 9344;                             // 80 bias floats

    prep_kernel<<<1, 256, 0, stream>>>(ew, eb, pw, pb, keys, Sy, Bg, cbf);
    fused_kernel<<<2048, 256, 0, stream>>>(X, Bg, thr, cbf, Sy);
    head_kernel<<<dim3(4, 32), 256, 0, stream>>>(Sy, fw, fb, lw, lb, out);
}